// Round 3
// baseline (110.691 us; speedup 1.0000x reference)
//
#include <hip/hip_runtime.h>
#include <float.h>

#define BATCH 128
#define IMS   64
#define NPIX  4096      // 64*64
#define LQ    10
#define LH    150
#define NACT  8

// ---- workspace layout (floats) ----
#define WS_RW    0                     // 18: collapsed r-conv weights [2][3][3]
#define WS_RB    18                    // 1 : collapsed bias
#define WS_FLAG  19                    // 1 : w-nonzero flag (0.0 / 1.0)
#define WS_R     32                    // BATCH*NPIX : r
#define WS_V     (32 + BATCH*NPIX)     // BATCH*NPIX : v

// ---- output layout (floats) ----
#define OUT_Q       0
#define OUT_LOGITS  (BATCH*LQ*NPIX)            // 5242880
#define OUT_ACTION  (OUT_LOGITS + BATCH*NACT)  // 5243904

// Kernel 1: collapse h->r into one 2x3x3 conv; compute w==0 flag.
__global__ void k_prep(const float* __restrict__ h_w, const float* __restrict__ h_b,
                       const float* __restrict__ r_w, const float* __restrict__ w,
                       float* __restrict__ ws) {
    int t = threadIdx.x;
    if (t < 18) {
        float s = 0.f;
        for (int c = 0; c < LH; ++c) s += r_w[c] * h_w[c * 18 + t];
        ws[WS_RW + t] = s;
    } else if (t == 18) {
        float s = 0.f;
        for (int c = 0; c < LH; ++c) s += r_w[c] * h_b[c];
        ws[WS_RB] = s;
    } else if (t == 19) {
        float nz = 0.f;
        for (int i = 0; i < LQ * 9; ++i) nz += fabsf(w[i]);
        ws[WS_FLAG] = (nz != 0.f) ? 1.f : 0.f;
    }
}

// Kernel 2: r = conv3x3(input, rw_eff) + rb   (one thread per pixel)
__global__ void k_rconv(const float* __restrict__ in, float* __restrict__ ws) {
    int idx = blockIdx.x * blockDim.x + threadIdx.x;   // b*NPIX + p
    int b = idx >> 12, p = idx & 4095;
    int i = p >> 6, j = p & 63;
    float wr[18];
#pragma unroll
    for (int t = 0; t < 18; ++t) wr[t] = ws[WS_RW + t];
    float acc = ws[WS_RB];
    const float* in0 = in + (size_t)b * 2 * NPIX;
#pragma unroll
    for (int c = 0; c < 2; ++c)
#pragma unroll
        for (int di = 0; di < 3; ++di) {
            int y = i + di - 1;
            if (y < 0 || y >= IMS) continue;
#pragma unroll
            for (int dj = 0; dj < 3; ++dj) {
                int x = j + dj - 1;
                if (x < 0 || x >= IMS) continue;
                acc += in0[c * NPIX + y * IMS + x] * wr[c * 9 + di * 3 + dj];
            }
        }
    ws[WS_R + idx] = acc;
}

// Kernel 3: q0 = conv3x3(r, q_w) -> out.q ; v = max_c q0 -> ws.v
__global__ void k_q0(const float* __restrict__ ws_r, const float* __restrict__ q_w,
                     float* __restrict__ out, float* __restrict__ ws) {
    int idx = blockIdx.x * blockDim.x + threadIdx.x;
    int b = idx >> 12, p = idx & 4095;
    int i = p >> 6, j = p & 63;
    const float* r = ws_r + WS_R + (size_t)b * NPIX;
    float nb[9];
#pragma unroll
    for (int di = 0; di < 3; ++di)
#pragma unroll
        for (int dj = 0; dj < 3; ++dj) {
            int y = i + di - 1, x = j + dj - 1;
            nb[di * 3 + dj] = (y < 0 || y >= IMS || x < 0 || x >= IMS)
                                  ? 0.f : r[y * IMS + x];
        }
    float vmax = -FLT_MAX;
    float* qb = out + OUT_Q + (size_t)b * LQ * NPIX + p;
#pragma unroll
    for (int c = 0; c < LQ; ++c) {
        float acc = 0.f;
#pragma unroll
        for (int u = 0; u < 9; ++u) acc += nb[u] * q_w[c * 9 + u];
        qb[c * NPIX] = acc;
        vmax = fmaxf(vmax, acc);
    }
    ws[WS_V + idx] = vmax;
}

// Kernel 4: value-iteration loop. One block per image, v kept in LDS.
// Early-exits uniformly when w == 0 (then v is already the fixed point).
__global__ void k_iter(const float* __restrict__ out_q, const float* __restrict__ w,
                       const int* __restrict__ kptr, float* __restrict__ ws) {
    if (ws[WS_FLAG] == 0.f) return;   // uniform across grid
    __shared__ float v[IMS][IMS];
    __shared__ float wsh[LQ * 9];
    int b = blockIdx.x, t = threadIdx.x;
    for (int p = t; p < NPIX; p += 256) v[p >> 6][p & 63] = ws[WS_V + b * NPIX + p];
    if (t < LQ * 9) wsh[t] = w[t];
    __syncthreads();
    int k = *kptr;
    const float* q0 = out_q + OUT_Q + (size_t)b * LQ * NPIX;
    for (int it = 0; it < k - 1; ++it) {
        float nv[16];
#pragma unroll
        for (int s = 0; s < 16; ++s) {
            int p = s * 256 + t;
            int i = p >> 6, j = p & 63;
            float nb[9];
#pragma unroll
            for (int di = 0; di < 3; ++di)
#pragma unroll
                for (int dj = 0; dj < 3; ++dj) {
                    int y = i + di - 1, x = j + dj - 1;
                    nb[di * 3 + dj] = (y < 0 || y >= IMS || x < 0 || x >= IMS)
                                          ? 0.f : v[y][x];
                }
            float m = -FLT_MAX;
#pragma unroll
            for (int c = 0; c < LQ; ++c) {
                float acc = q0[c * NPIX + p];
#pragma unroll
                for (int u = 0; u < 9; ++u) acc += nb[u] * wsh[c * 9 + u];
                m = fmaxf(m, acc);
            }
            nv[s] = m;
        }
        __syncthreads();
#pragma unroll
        for (int s = 0; s < 16; ++s) {
            int p = s * 256 + t;
            v[p >> 6][p & 63] = nv[s];
        }
        __syncthreads();
    }
    for (int p = t; p < NPIX; p += 256) ws[WS_V + b * NPIX + p] = v[p >> 6][p & 63];
}

// Kernel 5: q += conv3x3(v, w). No-op when w == 0 (q already equals q0).
__global__ void k_final(const float* __restrict__ ws, const float* __restrict__ w,
                        float* __restrict__ out) {
    if (ws[WS_FLAG] == 0.f) return;
    int idx = blockIdx.x * blockDim.x + threadIdx.x;
    int b = idx >> 12, p = idx & 4095;
    int i = p >> 6, j = p & 63;
    const float* v = ws + WS_V + (size_t)b * NPIX;
    float nb[9];
#pragma unroll
    for (int di = 0; di < 3; ++di)
#pragma unroll
        for (int dj = 0; dj < 3; ++dj) {
            int y = i + di - 1, x = j + dj - 1;
            nb[di * 3 + dj] = (y < 0 || y >= IMS || x < 0 || x >= IMS)
                                  ? 0.f : v[y * IMS + x];
        }
    float* qb = out + OUT_Q + (size_t)b * LQ * NPIX + p;
#pragma unroll
    for (int c = 0; c < LQ; ++c) {
        float acc = qb[c * NPIX];
#pragma unroll
        for (int u = 0; u < 9; ++u) acc += nb[u] * w[c * 9 + u];
        qb[c * NPIX] = acc;
    }
}

// Kernel 6: gather q at (state_x, state_y), FC -> logits, flat argmax -> action.
__global__ void k_head(const float* __restrict__ out_q, const int* __restrict__ sx,
                       const int* __restrict__ sy, const float* __restrict__ fc_w,
                       float* __restrict__ out) {
    __shared__ float lg[BATCH * NACT];
    __shared__ float bv[BATCH];
    __shared__ int bi[BATCH];
    int t = threadIdx.x;   // 128 threads
    if (t < BATCH) {
        int x = sx[t], y = sy[t];
        float qv[LQ];
#pragma unroll
        for (int c = 0; c < LQ; ++c)
            qv[c] = out_q[OUT_Q + ((size_t)t * LQ + c) * NPIX + x * IMS + y];
#pragma unroll
        for (int a = 0; a < NACT; ++a) {
            float s = 0.f;
#pragma unroll
            for (int c = 0; c < LQ; ++c) s += qv[c] * fc_w[a * LQ + c];
            lg[t * NACT + a] = s;
            out[OUT_LOGITS + t * NACT + a] = s;
        }
        float best = -FLT_MAX;
        int bidx = 0;
#pragma unroll
        for (int a = 0; a < NACT; ++a) {
            float vv = lg[t * NACT + a];
            if (vv > best) { best = vv; bidx = t * NACT + a; }
        }
        bv[t] = best;
        bi[t] = bidx;
    }
    __syncthreads();
    if (t == 0) {
        float mb = bv[0];
        int mi = bi[0];
        for (int u = 1; u < BATCH; ++u)
            if (bv[u] > mb) { mb = bv[u]; mi = bi[u]; }   // strict > keeps first index
        out[OUT_ACTION] = (float)mi;
    }
}

extern "C" void kernel_launch(void* const* d_in, const int* in_sizes, int n_in,
                              void* d_out, int out_size, void* d_ws, size_t ws_size,
                              hipStream_t stream) {
    const float* input = (const float*)d_in[0];
    const int*   sx    = (const int*)d_in[1];
    const int*   sy    = (const int*)d_in[2];
    const int*   kptr  = (const int*)d_in[3];
    const float* h_w   = (const float*)d_in[4];
    const float* h_b   = (const float*)d_in[5];
    const float* r_w   = (const float*)d_in[6];
    const float* q_w   = (const float*)d_in[7];
    const float* w     = (const float*)d_in[8];
    const float* fc_w  = (const float*)d_in[9];
    float* out = (float*)d_out;
    float* ws  = (float*)d_ws;

    k_prep <<<1, 64, 0, stream>>>(h_w, h_b, r_w, w, ws);
    k_rconv<<<BATCH * NPIX / 256, 256, 0, stream>>>(input, ws);
    k_q0   <<<BATCH * NPIX / 256, 256, 0, stream>>>(ws, q_w, out, ws);
    k_iter <<<BATCH, 256, 0, stream>>>(out, w, kptr, ws);
    k_final<<<BATCH * NPIX / 256, 256, 0, stream>>>(ws, w, out);
    k_head <<<1, 128, 0, stream>>>(out, sx, sy, fc_w, out);
}